// Round 3
// baseline (1358.114 us; speedup 1.0000x reference)
//
#include <hip/hip_runtime.h>
#include <cstdint>
#include <cstddef>

#define NAGENT 64
#define WAVES_PER_BLOCK 4

// Lookback state flags in bits 31:30. Poison 0xAAAAAAAA has bit30==0 -> INVALID,
// so the state array needs NO zero-initialization despite 0xAA re-poisoning.
#define FLAG_AGG    0x40000000u   // 01 | aggregate of this block
#define FLAG_PREFIX 0xC0000000u  // 11 | inclusive prefix through this block
#define VAL_MASK    0x3FFFFFFFu

// ---------------------------------------------------------------------------
// Single fused kernel.
//   blocks [0, EB)        : edge build (4 batches/block, 1 wave/batch) +
//                           decoupled-lookback scan + direct emit
//   blocks [EB, EB+CB)    : x = concat([obs, init]) elementwise, and -1 fill
//                           of the whole edge-index region (emit overwrites
//                           the first E slots; stream order irrelevant since
//                           regions touched by fill-then-emit are disjoint in
//                           time only via cache coherence within one dispatch?
//                           -> NO: fill and emit are concurrent here, so the
//                           -1 fill must NOT cover live edge slots. See note:
//                           fill covers [E, slots) is unknowable; instead
//                           emit blocks themselves fill their own batch's
//                           unused slots? Also unknowable (needs E).
//                           Resolution: fill writes -1 EVERYWHERE in the edge
//                           region, and edge blocks write their edges AFTER
//                           securing their prefix; racing writes to the same
//                           word with different values would be UB.
//                           => we serialize per-slot ownership: fill only
//                           writes slots >= FILL_START where FILL_START is the
//                           max possible E? Max E = slots. Doesn't work.
//                           => Final scheme: edge blocks write -1 padding for
//                           their OWN deficit... needs global E too.
//                           => Chosen scheme: the concat blocks fill the edge
//                           region, and edge emission is deferred to a SECOND
//                           wavefront-ordered pass within the same kernel via
//                           a device-scope arrival counter: the LAST block to
//                           finish its fill/adj work releases emission. That
//                           re-introduces a grid sync; instead we keep emit in
//                           this kernel but make fill and emit target disjoint
//                           slots by having edge block b fill slots
//                           [incl_prefix_b, 630*(b+1)+...) -- the pad gap that
//                           immediately follows its own edges up to the start
//                           of the next batch's edges is NOT contiguous.
// Simplest correct resolution (used below): the pad region [E, slots) equals
// the per-batch deficits laid end-to-end IN BATCH ORDER starting at E. Block b
// knows, after lookback, its exclusive prefix P_b and aggregate A_b. The LAST
// edge block (b == EB-1) knows E = P + A. It alone CANNOT fill 28 MB fast.
// => We give every edge block an equal slice of the fill work, gated on E
// being published by the last block: each edge block, after emitting, spins
// for state[EB-1] PREFIX (the total E), then fills its 1/EB slice of [E,slots).
// The spin resolves quickly since all edge blocks run early and the lookback
// chain completes in microseconds; slices are coalesced 256-thread fills.
// ---------------------------------------------------------------------------
__global__ __launch_bounds__(256) void fused_kernel(
    const float* __restrict__ obs, const float* __restrict__ ego,
    const float* __restrict__ oth, float* __restrict__ out,
    unsigned int* __restrict__ state,
    int B, int xtotal, int slots, int total)
{
    const int EB = B / WAVES_PER_BLOCK;      // edge blocks
    const int tid = threadIdx.x;

    if ((int)blockIdx.x >= EB) {
        // ---------------- concat path ----------------
        int i = ((int)blockIdx.x - EB) * 256 + tid;
        if (i >= xtotal) return;
        unsigned int ui = (unsigned int)i;
        unsigned int q = ui / 18u;          // row = b*64 + n
        unsigned int r = ui - q * 18u;      // col
        float v;
        if (r < 16u) {
            v = obs[(size_t)q * 16u + r];
        } else {
            const float* ini = ((q & 63u) == 0u) ? ego : oth;
            v = ini[r - 16u];
        }
        out[i] = v;
        return;
    }

    // ---------------- edge path ----------------
    const int wave = tid >> 6;
    const int lane = tid & 63;
    const int b = (int)blockIdx.x * WAVES_PER_BLOCK + wave;

    __shared__ int   order_s[WAVES_PER_BLOCK][NAGENT];
    __shared__ float ys_s[WAVES_PER_BLOCK][NAGENT];
    __shared__ unsigned int adj_s[WAVES_PER_BLOCK][NAGENT][2];
    __shared__ int   counts_s[WAVES_PER_BLOCK];
    __shared__ int   block_excl_s;

    // Load this agent's (x, y): first 8 bytes of its 64-byte obs row.
    const float2 p = *(const float2*)(obs + ((size_t)b * NAGENT + lane) * 16u);
    const float x = p.x;
    const float y = p.y;

    // Stable rank by x (tie-break: original index) — all-pairs via shfl.
    int rank = 0;
    #pragma unroll 8
    for (int j = 0; j < 64; ++j) {
        float xj = __shfl(x, j);
        rank += (xj < x || (xj == x && j < lane)) ? 1 : 0;
    }
    order_s[wave][rank] = lane;
    ys_s[wave][lane] = y;
    adj_s[wave][lane][0] = 0u;
    adj_s[wave][lane][1] = 0u;
    __syncthreads();

    // Lane = sorted position. 5 lane-band masks for that agent.
    const int a = order_s[wave][lane];
    const float ya = ys_s[wave][a];
    const float T1 = 1.0f / 3.0f;
    const float T2 = 2.0f / 3.0f;
    const bool m0 = (ya <= T1) && (ya > 0.0f);
    const bool m1 = (ya > T1) && (ya <= T2);
    const bool m2 = (ya >= T2) && (ya < 1.0f);
    bool ms[5];
    ms[0] = m0; ms[1] = m1; ms[2] = m2; ms[3] = m0 || m1; ms[4] = m1 || m2;

    #pragma unroll
    for (int k = 0; k < 5; ++k) {
        unsigned long long bits = __ballot(ms[k]);
        unsigned long long higher = (lane == 63) ? 0ULL : (bits >> (lane + 1));
        if (ms[k] && higher != 0ULL) {
            int q = lane + 1 + __builtin_ctzll(higher);
            int bb = order_s[wave][q];
            atomicOr(&adj_s[wave][a][bb >> 5], 1u << (bb & 31));
            atomicOr(&adj_s[wave][bb][a >> 5], 1u << (a & 31));
        }
    }
    __syncthreads();

    const unsigned int r0 = adj_s[wave][lane][0];
    const unsigned int r1 = adj_s[wave][lane][1];
    const int c = __popc(r0) + __popc(r1);

    // Inclusive wave prefix sum of row counts.
    int pre = c;
    #pragma unroll
    for (int off = 1; off < 64; off <<= 1) {
        int t = __shfl_up(pre, off);
        if (lane >= off) pre += t;
    }
    if (lane == 63) counts_s[wave] = pre;   // batch aggregate
    __syncthreads();

    // tid 0: decoupled lookback over block aggregates.
    if (tid == 0) {
        int agg = counts_s[0] + counts_s[1] + counts_s[2] + counts_s[3];
        int excl = 0;
        if (blockIdx.x == 0) {
            __hip_atomic_store(&state[0], FLAG_PREFIX | (unsigned int)agg,
                               __ATOMIC_RELEASE, __HIP_MEMORY_SCOPE_AGENT);
        } else {
            __hip_atomic_store(&state[blockIdx.x], FLAG_AGG | (unsigned int)agg,
                               __ATOMIC_RELEASE, __HIP_MEMORY_SCOPE_AGENT);
            int j = (int)blockIdx.x - 1;
            int run = 0;
            while (true) {
                unsigned int v = __hip_atomic_load(&state[j], __ATOMIC_ACQUIRE,
                                                   __HIP_MEMORY_SCOPE_AGENT);
                if (!(v & FLAG_AGG)) { __builtin_amdgcn_s_sleep(1); continue; }
                run += (int)(v & VAL_MASK);
                if (v & 0x80000000u) break;      // PREFIX reached
                --j;
            }
            excl = run;
            __hip_atomic_store(&state[blockIdx.x],
                               FLAG_PREFIX | (unsigned int)(run + agg),
                               __ATOMIC_RELEASE, __HIP_MEMORY_SCOPE_AGENT);
        }
        block_excl_s = excl;
    }
    __syncthreads();

    // Batch-level exclusive offset within the global edge list.
    int batch_excl = block_excl_s;
    for (int w = 0; w < WAVES_PER_BLOCK; ++w)
        if (w < wave) batch_excl += counts_s[w] - (w ? counts_s[w - 1] : 0);
    // counts_s holds inclusive per-wave? No: counts_s[w] is batch aggregate of
    // wave w (lane63's inclusive == total). Recompute simple sum:
    batch_excl = block_excl_s;
    #pragma unroll
    for (int w = 0; w < WAVES_PER_BLOCK; ++w)
        batch_excl += (w < wave) ? counts_s[w] : 0;

    float* out_es = out + xtotal;
    float* out_ed = out_es + slots;

    unsigned int w0 = r0, w1 = r1;
    int idx = batch_excl + pre - c;
    const int gbase = b * NAGENT;
    const float sg = (float)(gbase + lane);
    while (w0) {
        int d = __builtin_ctz(w0); w0 &= w0 - 1u;
        out_es[idx] = sg; out_ed[idx] = (float)(gbase + d); ++idx;
    }
    while (w1) {
        int d = 32 + __builtin_ctz(w1); w1 &= w1 - 1u;
        out_es[idx] = sg; out_ed[idx] = (float)(gbase + d); ++idx;
    }

    // ---- pad fill: wait for total E (last block's PREFIX), fill our slice ----
    __shared__ int E_s;
    if (tid == 0) {
        const int last = EB - 1;
        while (true) {
            unsigned int v = __hip_atomic_load(&state[last], __ATOMIC_ACQUIRE,
                                               __HIP_MEMORY_SCOPE_AGENT);
            if ((v & 0x80000000u) && (v & FLAG_AGG)) { E_s = (int)(v & VAL_MASK); break; }
            __builtin_amdgcn_s_sleep(2);
        }
    }
    __syncthreads();
    const int E = E_s;
    const int padN = slots - E;                       // elements per row to fill
    const int per = (padN + EB - 1) / EB;             // slice per edge block
    const int beg = E + (int)blockIdx.x * per;
    const int end = min(beg + per, slots);
    for (int i = beg + tid; i < end; i += 256) {
        out_es[i] = -1.0f;
        out_ed[i] = -1.0f;
    }
}

// ---------------------------------------------------------------------------
extern "C" void kernel_launch(void* const* d_in, const int* in_sizes, int n_in,
                              void* d_out, int out_size, void* d_ws, size_t ws_size,
                              hipStream_t stream)
{
    const float* obs = (const float*)d_in[0];
    const float* ego = (const float*)d_in[1];
    const float* oth = (const float*)d_in[2];

    const int B = in_sizes[0] / (NAGENT * 16);        // 8192
    const int M = B * NAGENT;                          // 524288
    const int xtotal = M * 18;                         // 9437184
    const int slots = B * 10 * (NAGENT - 1);           // 5160960
    const int total = xtotal + 2 * slots;

    unsigned int* state = (unsigned int*)d_ws;         // EB entries, poison-safe

    const int EB = B / WAVES_PER_BLOCK;                // 2048 edge blocks
    const int CB = (xtotal + 255) / 256;               // 36864 concat blocks
    fused_kernel<<<EB + CB, 256, 0, stream>>>(
        obs, ego, oth, (float*)d_out, state, B, xtotal, slots, total);
}

// Round 4
// 138.886 us; speedup vs baseline: 9.7786x; 9.7786x over previous
//
#include <hip/hip_runtime.h>
#include <cstdint>
#include <cstddef>

#define NAGENT 64
#define WPB 4          // batches (waves) per block in build/emit
#define ROWS_K1 128    // rows per block in concat
#define CAP 640        // LDS staging capacity per batch (>= 630)
#define SLOT_PB 630    // 10*(NAGENT-1) output slots per batch

// ---------------------------------------------------------------------------
// K1: x = concat([obs, init], -1), LDS-staged so both the global read and the
// global write are dense coalesced float4. Also emits compact xy[] for K2.
// 128 rows/block: read 512 float4, write 576 float4.
// ---------------------------------------------------------------------------
__global__ __launch_bounds__(256) void concat_kernel(
    const float4* __restrict__ obs4, const float* __restrict__ ego,
    const float* __restrict__ oth, float4* __restrict__ out4,
    float* __restrict__ xy)
{
    __shared__ float buf[ROWS_K1 * 16];
    const int t = threadIdx.x;
    const int R0 = blockIdx.x * ROWS_K1;          // R0 % 64 == 0 always

    const float4* src = obs4 + (size_t)R0 * 4;    // 4 float4 per 16-float row
    ((float4*)buf)[t]       = src[t];
    ((float4*)buf)[t + 256] = src[t + 256];
    const float e0 = ego[0], e1 = ego[1];
    const float o0 = oth[0], o1 = oth[1];
    __syncthreads();

    float4* dst = out4 + (size_t)blockIdx.x * 576;   // 128*18/4 per block
    #pragma unroll
    for (int k = 0; k < 3; ++k) {
        const int f = t + k * 256;
        if (f >= 576) break;                      // only 64 threads take k==2
        float4 v;
        float* vp = (float*)&v;
        #pragma unroll
        for (int c = 0; c < 4; ++c) {
            const unsigned g   = (unsigned)(f * 4 + c);
            const unsigned row = g / 18u;
            const unsigned col = g - row * 18u;
            float val;
            if (col < 16u) {
                val = buf[row * 16u + col];
                if (col < 2u) xy[((size_t)R0 + row) * 2u + col] = val;
            } else {
                const bool egorow = ((row & 63u) == 0u);
                val = (col == 16u) ? (egorow ? e0 : o0) : (egorow ? e1 : o1);
            }
            vp[c] = val;
        }
        dst[f] = v;
    }
}

// ---------------------------------------------------------------------------
// K2: per-batch edge construction. One wave per batch, 4 batches/block.
// 64x64 adjacency bitmask in LDS (dedupe + (src,dst)-lex order for free),
// written out as 2 u32 per row + per-batch edge count.
// ---------------------------------------------------------------------------
__global__ __launch_bounds__(64 * WPB) void build_kernel(
    const float2* __restrict__ xy, unsigned int* __restrict__ adj_g,
    int* __restrict__ counts, int B)
{
    const int wave = threadIdx.x >> 6;
    const int lane = threadIdx.x & 63;
    const int b = blockIdx.x * WPB + wave;

    __shared__ int   order_s[WPB][NAGENT];
    __shared__ float ys_s[WPB][NAGENT];
    __shared__ unsigned int adj_s[WPB][NAGENT][2];

    const float2 p = xy[(size_t)b * NAGENT + lane];
    const float x = p.x;
    const float y = p.y;

    // Stable rank by x (tie-break: original index) — all-pairs via shfl.
    int rank = 0;
    #pragma unroll 8
    for (int j = 0; j < 64; ++j) {
        float xj = __shfl(x, j);
        rank += (xj < x || (xj == x && j < lane)) ? 1 : 0;
    }
    order_s[wave][rank] = lane;
    ys_s[wave][lane] = y;
    adj_s[wave][lane][0] = 0u;
    adj_s[wave][lane][1] = 0u;
    __syncthreads();

    // Lane = sorted position. 5 lane-band masks for that agent.
    const int a = order_s[wave][lane];
    const float ya = ys_s[wave][a];
    const float T1 = 1.0f / 3.0f;   // == f32(1/3) in the reference
    const float T2 = 2.0f / 3.0f;
    const bool m0 = (ya <= T1) && (ya > 0.0f);
    const bool m1 = (ya > T1) && (ya <= T2);
    const bool m2 = (ya >= T2) && (ya < 1.0f);
    bool ms[5];
    ms[0] = m0; ms[1] = m1; ms[2] = m2; ms[3] = m0 || m1; ms[4] = m1 || m2;

    #pragma unroll
    for (int k = 0; k < 5; ++k) {
        unsigned long long bits = __ballot(ms[k]);
        unsigned long long higher = (lane == 63) ? 0ULL : (bits >> (lane + 1));
        if (ms[k] && higher != 0ULL) {
            int q = lane + 1 + __builtin_ctzll(higher);
            int bb = order_s[wave][q];
            atomicOr(&adj_s[wave][a][bb >> 5], 1u << (bb & 31));
            atomicOr(&adj_s[wave][bb][a >> 5], 1u << (a & 31));
        }
    }
    __syncthreads();

    const unsigned int r0 = adj_s[wave][lane][0];
    const unsigned int r1 = adj_s[wave][lane][1];
    adj_g[(size_t)b * 128 + 2 * lane + 0] = r0;
    adj_g[(size_t)b * 128 + 2 * lane + 1] = r1;

    int c = __popc(r0) + __popc(r1);
    #pragma unroll
    for (int off = 1; off < 64; off <<= 1) {
        int t = __shfl_up(c, off);
        if (lane >= off) c += t;
    }
    if (lane == 63) counts[b] = c;
}

// ---------------------------------------------------------------------------
// K3: emit + pad, NO separate scan dispatch. Each wave (batch b) computes its
// own prefix (edge placement) and suffix (pad placement) over counts[] with
// 128 coalesced L1-hot loads + shuffle reductions. Pad slices are anchored
// from the END of the slot region: X_b = 630*(B-1-b) - suffix_gt(b);
// batch b fills [slots - X_b - D_b, slots - X_b). These tile [E, slots)
// exactly (X_{b-1} = X_b + D_b), so no block needs global E.
// Edges staged in LDS, then written coalesced.
// ---------------------------------------------------------------------------
__global__ __launch_bounds__(64 * WPB) void emit_kernel(
    const unsigned int* __restrict__ adj_g, const int* __restrict__ counts,
    float* __restrict__ out_es, float* __restrict__ out_ed, int B, int slots)
{
    __shared__ float es_s[WPB][CAP];
    __shared__ float ed_s[WPB][CAP];
    const int wave = threadIdx.x >> 6;
    const int lane = threadIdx.x & 63;
    const int b = blockIdx.x * WPB + wave;

    // Per-lane partial prefix/total over counts, then butterfly reduce.
    int pre = 0, tot = 0;
    for (int i = lane; i < B; i += 64) {
        const int v = counts[i];
        tot += v;
        pre += (i < b) ? v : 0;
    }
    #pragma unroll
    for (int off = 32; off >= 1; off >>= 1) {
        pre += __shfl_xor(pre, off);
        tot += __shfl_xor(tot, off);
    }
    const int cnt = counts[b];
    const int suf = tot - pre - cnt;          // sum of counts after b

    // Enumerate this row's adjacency bits into LDS staging.
    unsigned int r0 = adj_g[(size_t)b * 128 + 2 * lane + 0];
    unsigned int r1 = adj_g[(size_t)b * 128 + 2 * lane + 1];
    const int c = __popc(r0) + __popc(r1);
    int inc = c;
    #pragma unroll
    for (int off = 1; off < 64; off <<= 1) {
        int t = __shfl_up(inc, off);
        if (lane >= off) inc += t;
    }
    int pos = inc - c;
    const int gbase = b * NAGENT;
    const float sg = (float)(gbase + lane);
    while (r0) {
        int d = __builtin_ctz(r0); r0 &= r0 - 1u;
        es_s[wave][pos] = sg; ed_s[wave][pos] = (float)(gbase + d); ++pos;
    }
    while (r1) {
        int d = 32 + __builtin_ctz(r1); r1 &= r1 - 1u;
        es_s[wave][pos] = sg; ed_s[wave][pos] = (float)(gbase + d); ++pos;
    }
    __syncthreads();

    // Coalesced edge write at [pre, pre+cnt).
    for (int j = lane; j < cnt; j += 64) {
        out_es[pre + j] = es_s[wave][j];
        out_ed[pre + j] = ed_s[wave][j];
    }
    // Pad slice write (batch-owned, end-anchored).
    const int D = SLOT_PB - cnt;
    const int X = SLOT_PB * (B - 1 - b) - suf;
    const int pbeg = slots - X - D;
    for (int j = lane; j < D; j += 64) {
        out_es[pbeg + j] = -1.0f;
        out_ed[pbeg + j] = -1.0f;
    }
}

// ---------------------------------------------------------------------------
extern "C" void kernel_launch(void* const* d_in, const int* in_sizes, int n_in,
                              void* d_out, int out_size, void* d_ws, size_t ws_size,
                              hipStream_t stream)
{
    const float* obs = (const float*)d_in[0];
    const float* ego = (const float*)d_in[1];
    const float* oth = (const float*)d_in[2];

    const int B = in_sizes[0] / (NAGENT * 16);        // 8192
    const int M = B * NAGENT;                          // 524288 rows
    const int xtotal = M * 18;                         // 9437184
    const int slots = B * SLOT_PB;                     // 5160960

    float* out_x  = (float*)d_out;
    float* out_es = out_x + xtotal;
    float* out_ed = out_es + slots;

    // ws layout: xy[2*M floats] | adj[B*128 u32] | counts[B int]
    float*        xy     = (float*)d_ws;
    unsigned int* adj_g  = (unsigned int*)(xy + (size_t)2 * M);
    int*          counts = (int*)(adj_g + (size_t)B * 128);

    concat_kernel<<<M / ROWS_K1, 256, 0, stream>>>(
        (const float4*)obs, ego, oth, (float4*)d_out, xy);
    build_kernel<<<B / WPB, 64 * WPB, 0, stream>>>(
        (const float2*)xy, adj_g, counts, B);
    emit_kernel<<<B / WPB, 64 * WPB, 0, stream>>>(
        adj_g, counts, out_es, out_ed, B, slots);
}

// Round 5
// 124.837 us; speedup vs baseline: 10.8791x; 1.1125x over previous
//
#include <hip/hip_runtime.h>
#include <cstdint>
#include <cstddef>

#define NAGENT 64
#define WPB 4          // batches (waves) per block
#define ROWS_A 256     // rows per block in fused concat+build (= 4 batches)
#define CAP 640        // LDS staging capacity per batch (>= 630)
#define SLOT_PB 630    // 10*(NAGENT-1) output slots per batch

// ---------------------------------------------------------------------------
// Kernel A: fused concat + edge-build. 256 rows (= 4 batches) per block.
//  - stage 256 obs rows in LDS (coalesced float4), capturing (x,y) per row
//  - write x = concat([obs, init]) as dense coalesced float4
//  - per wave: build one batch's 64x64 adjacency bitmask (dedupe +
//    (src,dst)-lex order for free), write 8B/row + per-batch count
// ---------------------------------------------------------------------------
__global__ __launch_bounds__(256) void concat_build_kernel(
    const float4* __restrict__ obs4, const float* __restrict__ ego,
    const float* __restrict__ oth, float4* __restrict__ out4,
    uint2* __restrict__ adj_g, int* __restrict__ counts)
{
    __shared__ float  buf[ROWS_A * 16];       // 16 KB staged rows
    __shared__ float2 xy_s[ROWS_A];           // 2 KB compact (x,y)
    __shared__ int    order_s[WPB][NAGENT];   // 1 KB rank -> agent
    __shared__ unsigned int adj_s[WPB][NAGENT][2];  // 2 KB bitmatrix

    const int t = threadIdx.x;
    const int wave = t >> 6;
    const int lane = t & 63;

    adj_s[wave][lane][0] = 0u;
    adj_s[wave][lane][1] = 0u;

    // Stage: 1024 float4 loads; float4 #0 of each row carries (x,y).
    const float4* src = obs4 + (size_t)blockIdx.x * (ROWS_A * 4);
    #pragma unroll
    for (int k = 0; k < 4; ++k) {
        const int f = t + k * 256;
        float4 v = src[f];
        ((float4*)buf)[f] = v;
        if ((f & 3) == 0) xy_s[f >> 2] = make_float2(v.x, v.y);
    }
    const float e0 = ego[0], e1 = ego[1];
    const float o0 = oth[0], o1 = oth[1];
    __syncthreads();

    // Concat write: 1152 float4 per block, fully coalesced.
    float4* dst = out4 + (size_t)blockIdx.x * (ROWS_A * 18 / 4);
    #pragma unroll
    for (int k = 0; k < 5; ++k) {
        const int f = t + k * 256;
        if (f >= ROWS_A * 18 / 4) break;
        float4 v;
        float* vp = (float*)&v;
        #pragma unroll
        for (int c = 0; c < 4; ++c) {
            const unsigned g   = (unsigned)(f * 4 + c);
            const unsigned row = g / 18u;
            const unsigned col = g - row * 18u;
            float val;
            if (col < 16u) {
                val = buf[row * 16u + col];
            } else {
                const bool eg = ((row & 63u) == 0u);
                val = (col == 16u) ? (eg ? e0 : o0) : (eg ? e1 : o1);
            }
            vp[c] = val;
        }
        dst[f] = v;
    }

    // Build: one wave per batch.
    const int b = blockIdx.x * WPB + wave;
    const float2 p = xy_s[wave * 64 + lane];
    const float x = p.x;

    // Stable rank by x (tie-break: original index) — all-pairs via shfl.
    int rank = 0;
    #pragma unroll 8
    for (int j = 0; j < 64; ++j) {
        float xj = __shfl(x, j);
        rank += (xj < x || (xj == x && j < lane)) ? 1 : 0;
    }
    order_s[wave][rank] = lane;
    __syncthreads();

    // Lane = sorted position. 5 lane-band masks for that agent.
    const int a = order_s[wave][lane];
    const float ya = xy_s[wave * 64 + a].y;
    const float T1 = 1.0f / 3.0f;   // == f32(1/3) in the reference
    const float T2 = 2.0f / 3.0f;
    const bool m0 = (ya <= T1) && (ya > 0.0f);
    const bool m1 = (ya > T1) && (ya <= T2);
    const bool m2 = (ya >= T2) && (ya < 1.0f);
    bool ms[5];
    ms[0] = m0; ms[1] = m1; ms[2] = m2; ms[3] = m0 || m1; ms[4] = m1 || m2;

    #pragma unroll
    for (int k = 0; k < 5; ++k) {
        unsigned long long bits = __ballot(ms[k]);
        unsigned long long higher = (lane == 63) ? 0ULL : (bits >> (lane + 1));
        if (ms[k] && higher != 0ULL) {
            int q = lane + 1 + __builtin_ctzll(higher);
            int bb = order_s[wave][q];
            atomicOr(&adj_s[wave][a][bb >> 5], 1u << (bb & 31));
            atomicOr(&adj_s[wave][bb][a >> 5], 1u << (a & 31));
        }
    }
    __syncthreads();

    const unsigned int r0 = adj_s[wave][lane][0];
    const unsigned int r1 = adj_s[wave][lane][1];
    adj_g[(size_t)b * NAGENT + lane] = make_uint2(r0, r1);

    int c = __popc(r0) + __popc(r1);
    #pragma unroll
    for (int off = 32; off >= 1; off >>= 1) c += __shfl_xor(c, off);
    if (lane == 0) counts[b] = c;
}

// ---------------------------------------------------------------------------
// Kernel B: emit + pad, no scan dispatch. Each wave (batch b) computes its
// own prefix (edge placement) and suffix (pad placement) over counts[] via
// int4 loads + butterfly reduction. Pad slices anchored from the END:
// X_b = 630*(B-1-b) - suffix_gt(b); batch b fills
// [slots - X_b - D_b, slots - X_b) — these tile [E, slots) exactly, so no
// block needs global E. Edges staged in LDS, written as aligned float4.
// ---------------------------------------------------------------------------
__global__ __launch_bounds__(64 * WPB) void emit_kernel(
    const uint2* __restrict__ adj_g, const int* __restrict__ counts,
    float* __restrict__ out_es, float* __restrict__ out_ed, int B, int slots)
{
    __shared__ float es_s[WPB][CAP];
    __shared__ float ed_s[WPB][CAP];
    const int wave = threadIdx.x >> 6;
    const int lane = threadIdx.x & 63;
    const int b = blockIdx.x * WPB + wave;

    // Per-lane partial prefix/total over counts (int4), butterfly reduce.
    int pre = 0, tot = 0;
    const int4* c4 = (const int4*)counts;
    for (int i = lane; i < B / 4; i += 64) {
        const int4 v = c4[i];
        const int base = 4 * i;
        tot += v.x + v.y + v.z + v.w;
        pre += ((base + 0 < b) ? v.x : 0) + ((base + 1 < b) ? v.y : 0)
             + ((base + 2 < b) ? v.z : 0) + ((base + 3 < b) ? v.w : 0);
    }
    #pragma unroll
    for (int off = 32; off >= 1; off >>= 1) {
        pre += __shfl_xor(pre, off);
        tot += __shfl_xor(tot, off);
    }
    const int cnt = counts[b];
    const int suf = tot - pre - cnt;          // sum of counts after b

    // Enumerate this row's adjacency bits into LDS staging.
    const uint2 ar = adj_g[(size_t)b * NAGENT + lane];
    unsigned int r0 = ar.x, r1 = ar.y;
    const int c = __popc(r0) + __popc(r1);
    int inc = c;
    #pragma unroll
    for (int off = 1; off < 64; off <<= 1) {
        int t = __shfl_up(inc, off);
        if (lane >= off) inc += t;
    }
    int pos = inc - c;
    const int gbase = b * NAGENT;
    const float sg = (float)(gbase + lane);
    while (r0) {
        int d = __builtin_ctz(r0); r0 &= r0 - 1u;
        es_s[wave][pos] = sg; ed_s[wave][pos] = (float)(gbase + d); ++pos;
    }
    while (r1) {
        int d = 32 + __builtin_ctz(r1); r1 &= r1 - 1u;
        es_s[wave][pos] = sg; ed_s[wave][pos] = (float)(gbase + d); ++pos;
    }
    __syncthreads();

    // ---- Edge write at [pre, pre+cnt): scalar head to 16B align, f4 body ----
    {
        int h = (4 - (pre & 3)) & 3;
        if (h > cnt) h = cnt;
        for (int j = lane; j < h; j += 64) {
            out_es[pre + j] = es_s[wave][j];
            out_ed[pre + j] = ed_s[wave][j];
        }
        const int body = (cnt - h) >> 2;      // # of float4 groups
        float4* oes4 = (float4*)(out_es + pre + h);
        float4* oed4 = (float4*)(out_ed + pre + h);
        for (int q = lane; q < body; q += 64) {
            const int j = h + 4 * q;
            float4 v, w;
            v.x = es_s[wave][j];     w.x = ed_s[wave][j];
            v.y = es_s[wave][j + 1]; w.y = ed_s[wave][j + 1];
            v.z = es_s[wave][j + 2]; w.z = ed_s[wave][j + 2];
            v.w = es_s[wave][j + 3]; w.w = ed_s[wave][j + 3];
            oes4[q] = v;
            oed4[q] = w;
        }
        for (int j = h + 4 * body + lane; j < cnt; j += 64) {
            out_es[pre + j] = es_s[wave][j];
            out_ed[pre + j] = ed_s[wave][j];
        }
    }

    // ---- Pad slice write (batch-owned, end-anchored), vectorized -1 fill ----
    {
        const int D = SLOT_PB - cnt;
        const int X = SLOT_PB * (B - 1 - b) - suf;
        const int pbeg = slots - X - D;
        int h = (4 - (pbeg & 3)) & 3;
        if (h > D) h = D;
        for (int j = lane; j < h; j += 64) {
            out_es[pbeg + j] = -1.0f;
            out_ed[pbeg + j] = -1.0f;
        }
        const int body = (D - h) >> 2;
        float4* oes4 = (float4*)(out_es + pbeg + h);
        float4* oed4 = (float4*)(out_ed + pbeg + h);
        const float4 neg1 = make_float4(-1.0f, -1.0f, -1.0f, -1.0f);
        for (int q = lane; q < body; q += 64) {
            oes4[q] = neg1;
            oed4[q] = neg1;
        }
        for (int j = h + 4 * body + lane; j < D; j += 64) {
            out_es[pbeg + j] = -1.0f;
            out_ed[pbeg + j] = -1.0f;
        }
    }
}

// ---------------------------------------------------------------------------
extern "C" void kernel_launch(void* const* d_in, const int* in_sizes, int n_in,
                              void* d_out, int out_size, void* d_ws, size_t ws_size,
                              hipStream_t stream)
{
    const float* obs = (const float*)d_in[0];
    const float* ego = (const float*)d_in[1];
    const float* oth = (const float*)d_in[2];

    const int B = in_sizes[0] / (NAGENT * 16);        // 8192
    const int M = B * NAGENT;                          // 524288 rows
    const int xtotal = M * 18;                         // 9437184
    const int slots = B * SLOT_PB;                     // 5160960

    float* out_x  = (float*)d_out;
    float* out_es = out_x + xtotal;
    float* out_ed = out_es + slots;

    // ws layout: adj[B*64 uint2] | counts[B int]
    uint2* adj_g  = (uint2*)d_ws;
    int*   counts = (int*)(adj_g + (size_t)B * NAGENT);

    concat_build_kernel<<<M / ROWS_A, 256, 0, stream>>>(
        (const float4*)obs, ego, oth, (float4*)d_out, adj_g, counts);
    emit_kernel<<<B / WPB, 64 * WPB, 0, stream>>>(
        adj_g, counts, out_es, out_ed, B, slots);
}

// Round 7
// 120.523 us; speedup vs baseline: 11.2685x; 1.0358x over previous
//
#include <hip/hip_runtime.h>
#include <cstdint>
#include <cstddef>

#define NAGENT 64
#define WPB 4          // batches (waves) per block
#define ROWS_A 256     // rows per block in fused concat+build (= 4 batches)
#define CAP 640        // LDS staging capacity per batch (>= 630)
#define SLOT_PB 630    // 10*(NAGENT-1) output slots per batch

// ---------------------------------------------------------------------------
// Kernel A: fused concat + edge-build. 256 rows (= 4 batches) per block.
//  - stage 256 obs rows in LDS (coalesced float4), capturing (x,y) per row
//  - write x = concat([obs, init]) as dense coalesced float4
//  - per wave: build one batch's 64x64 adjacency bitmask (dedupe +
//    (src,dst)-lex order for free), write 8B/row + per-batch count
// (Identical to the round-5 version, which passed with absmax 0.)
// ---------------------------------------------------------------------------
__global__ __launch_bounds__(256) void concat_build_kernel(
    const float4* __restrict__ obs4, const float* __restrict__ ego,
    const float* __restrict__ oth, float4* __restrict__ out4,
    uint2* __restrict__ adj_g, int* __restrict__ counts)
{
    __shared__ float  buf[ROWS_A * 16];       // 16 KB staged rows
    __shared__ float2 xy_s[ROWS_A];           // 2 KB compact (x,y)
    __shared__ int    order_s[WPB][NAGENT];   // 1 KB rank -> agent
    __shared__ unsigned int adj_s[WPB][NAGENT][2];  // 2 KB bitmatrix

    const int t = threadIdx.x;
    const int wave = t >> 6;
    const int lane = t & 63;

    adj_s[wave][lane][0] = 0u;
    adj_s[wave][lane][1] = 0u;

    // Stage: 1024 float4 loads; float4 #0 of each row carries (x,y).
    const float4* src = obs4 + (size_t)blockIdx.x * (ROWS_A * 4);
    #pragma unroll
    for (int k = 0; k < 4; ++k) {
        const int f = t + k * 256;
        float4 v = src[f];
        ((float4*)buf)[f] = v;
        if ((f & 3) == 0) xy_s[f >> 2] = make_float2(v.x, v.y);
    }
    const float e0 = ego[0], e1 = ego[1];
    const float o0 = oth[0], o1 = oth[1];
    __syncthreads();

    // Concat write: 1152 float4 per block, fully coalesced.
    float4* dst = out4 + (size_t)blockIdx.x * (ROWS_A * 18 / 4);
    #pragma unroll
    for (int k = 0; k < 5; ++k) {
        const int f = t + k * 256;
        if (f >= ROWS_A * 18 / 4) break;
        float4 v;
        float* vp = (float*)&v;
        #pragma unroll
        for (int c = 0; c < 4; ++c) {
            const unsigned g   = (unsigned)(f * 4 + c);
            const unsigned row = g / 18u;
            const unsigned col = g - row * 18u;
            float val;
            if (col < 16u) {
                val = buf[row * 16u + col];
            } else {
                const bool eg = ((row & 63u) == 0u);
                val = (col == 16u) ? (eg ? e0 : o0) : (eg ? e1 : o1);
            }
            vp[c] = val;
        }
        dst[f] = v;
    }

    // Build: one wave per batch.
    const int b = blockIdx.x * WPB + wave;
    const float2 p = xy_s[wave * 64 + lane];
    const float x = p.x;

    // Stable rank by x (tie-break: original index) — all-pairs via shfl.
    int rank = 0;
    #pragma unroll 8
    for (int j = 0; j < 64; ++j) {
        float xj = __shfl(x, j);
        rank += (xj < x || (xj == x && j < lane)) ? 1 : 0;
    }
    order_s[wave][rank] = lane;
    __syncthreads();

    // Lane = sorted position. 5 lane-band masks for that agent.
    const int a = order_s[wave][lane];
    const float ya = xy_s[wave * 64 + a].y;
    const float T1 = 1.0f / 3.0f;   // == f32(1/3) in the reference
    const float T2 = 2.0f / 3.0f;
    const bool m0 = (ya <= T1) && (ya > 0.0f);
    const bool m1 = (ya > T1) && (ya <= T2);
    const bool m2 = (ya >= T2) && (ya < 1.0f);
    bool ms[5];
    ms[0] = m0; ms[1] = m1; ms[2] = m2; ms[3] = m0 || m1; ms[4] = m1 || m2;

    #pragma unroll
    for (int k = 0; k < 5; ++k) {
        unsigned long long bits = __ballot(ms[k]);
        unsigned long long higher = (lane == 63) ? 0ULL : (bits >> (lane + 1));
        if (ms[k] && higher != 0ULL) {
            int q = lane + 1 + __builtin_ctzll(higher);
            int bb = order_s[wave][q];
            atomicOr(&adj_s[wave][a][bb >> 5], 1u << (bb & 31));
            atomicOr(&adj_s[wave][bb][a >> 5], 1u << (a & 31));
        }
    }
    __syncthreads();

    const unsigned int r0 = adj_s[wave][lane][0];
    const unsigned int r1 = adj_s[wave][lane][1];
    adj_g[(size_t)b * NAGENT + lane] = make_uint2(r0, r1);

    int c = __popc(r0) + __popc(r1);
    #pragma unroll
    for (int off = 32; off >= 1; off >>= 1) c += __shfl_xor(c, off);
    if (lane == 0) counts[b] = c;
}

// ---------------------------------------------------------------------------
// Kernel B: emit + pad, no scan dispatch. The counts scan is now BLOCK-
// cooperative (R5 did it per-wave: 4x redundant, 256 MB of L2 reads; this
// version reads 64 MB): 256 threads scan counts via int4, reduce through
// LDS, then each wave derives its batch's pre/suf with 3 L1-hot loads.
// Pad slices anchored from the END: X_b = 630*(B-1-b) - suffix_gt(b);
// batch b fills [slots - X_b - D_b, slots - X_b) — these tile [E, slots)
// exactly, so no block needs global E. Edges staged in LDS, aligned-f4 out.
// ---------------------------------------------------------------------------
__global__ __launch_bounds__(256) void emit_kernel(
    const uint2* __restrict__ adj_g, const int* __restrict__ counts,
    float* __restrict__ out_es, float* __restrict__ out_ed, int B, int slots)
{
    __shared__ float es_s[WPB][CAP];
    __shared__ float ed_s[WPB][CAP];
    __shared__ int   red_s[2 * WPB];
    const int t = threadIdx.x;
    const int wave = t >> 6;
    const int lane = t & 63;
    const int b0 = blockIdx.x * WPB;
    const int b = b0 + wave;

    // Block-cooperative prefix/total over counts (8 int4 per thread).
    int p = 0, tot = 0;
    const int4* c4 = (const int4*)counts;
    for (int i = t; i < B / 4; i += 256) {
        const int4 v = c4[i];
        const int s = v.x + v.y + v.z + v.w;
        tot += s;
        if (4 * i < b0) p += s;       // b0 % 4 == 0 -> int4-granular exact
    }
    #pragma unroll
    for (int off = 32; off >= 1; off >>= 1) {
        p   += __shfl_xor(p, off);
        tot += __shfl_xor(tot, off);
    }
    if (lane == 0) { red_s[wave] = p; red_s[WPB + wave] = tot; }
    __syncthreads();
    p   = red_s[0] + red_s[1] + red_s[2] + red_s[3];
    tot = red_s[WPB] + red_s[WPB + 1] + red_s[WPB + 2] + red_s[WPB + 3];

    const int cnt = counts[b];        // L1-hot
    int pre = p;
    #pragma unroll
    for (int w = 0; w < WPB; ++w)
        if (w < wave) pre += counts[b0 + w];
    const int suf = tot - pre - cnt;  // sum of counts after b

    // Enumerate this row's adjacency bits into LDS staging.
    const uint2 ar = adj_g[(size_t)b * NAGENT + lane];
    unsigned int r0 = ar.x, r1 = ar.y;
    const int c = __popc(r0) + __popc(r1);
    int inc = c;
    #pragma unroll
    for (int off = 1; off < 64; off <<= 1) {
        int v = __shfl_up(inc, off);
        if (lane >= off) inc += v;
    }
    int pos = inc - c;
    const int gbase = b * NAGENT;
    const float sg = (float)(gbase + lane);
    while (r0) {
        int d = __builtin_ctz(r0); r0 &= r0 - 1u;
        es_s[wave][pos] = sg; ed_s[wave][pos] = (float)(gbase + d); ++pos;
    }
    while (r1) {
        int d = 32 + __builtin_ctz(r1); r1 &= r1 - 1u;
        es_s[wave][pos] = sg; ed_s[wave][pos] = (float)(gbase + d); ++pos;
    }
    __syncthreads();

    // ---- Edge write at [pre, pre+cnt): scalar head to 16B align, f4 body ----
    {
        int h = (4 - (pre & 3)) & 3;
        if (h > cnt) h = cnt;
        for (int j = lane; j < h; j += 64) {
            out_es[pre + j] = es_s[wave][j];
            out_ed[pre + j] = ed_s[wave][j];
        }
        const int body = (cnt - h) >> 2;      // # of float4 groups
        float4* oes4 = (float4*)(out_es + pre + h);
        float4* oed4 = (float4*)(out_ed + pre + h);
        for (int q = lane; q < body; q += 64) {
            const int j = h + 4 * q;
            float4 v, w;
            v.x = es_s[wave][j];     w.x = ed_s[wave][j];
            v.y = es_s[wave][j + 1]; w.y = ed_s[wave][j + 1];
            v.z = es_s[wave][j + 2]; w.z = ed_s[wave][j + 2];
            v.w = es_s[wave][j + 3]; w.w = ed_s[wave][j + 3];
            oes4[q] = v;
            oed4[q] = w;
        }
        for (int j = h + 4 * body + lane; j < cnt; j += 64) {
            out_es[pre + j] = es_s[wave][j];
            out_ed[pre + j] = ed_s[wave][j];
        }
    }

    // ---- Pad slice write (batch-owned, end-anchored), vectorized -1 fill ----
    {
        const int D = SLOT_PB - cnt;
        const int X = SLOT_PB * (B - 1 - b) - suf;
        const int pbeg = slots - X - D;
        int h = (4 - (pbeg & 3)) & 3;
        if (h > D) h = D;
        for (int j = lane; j < h; j += 64) {
            out_es[pbeg + j] = -1.0f;
            out_ed[pbeg + j] = -1.0f;
        }
        const int body = (D - h) >> 2;
        float4* oes4 = (float4*)(out_es + pbeg + h);
        float4* oed4 = (float4*)(out_ed + pbeg + h);
        const float4 neg1 = make_float4(-1.0f, -1.0f, -1.0f, -1.0f);
        for (int q = lane; q < body; q += 64) {
            oes4[q] = neg1;
            oed4[q] = neg1;
        }
        for (int j = h + 4 * body + lane; j < D; j += 64) {
            out_es[pbeg + j] = -1.0f;
            out_ed[pbeg + j] = -1.0f;
        }
    }
}

// ---------------------------------------------------------------------------
extern "C" void kernel_launch(void* const* d_in, const int* in_sizes, int n_in,
                              void* d_out, int out_size, void* d_ws, size_t ws_size,
                              hipStream_t stream)
{
    const float* obs = (const float*)d_in[0];
    const float* ego = (const float*)d_in[1];
    const float* oth = (const float*)d_in[2];

    const int B = in_sizes[0] / (NAGENT * 16);        // 8192
    const int M = B * NAGENT;                          // 524288 rows
    const int xtotal = M * 18;                         // 9437184
    const int slots = B * SLOT_PB;                     // 5160960

    float* out_x  = (float*)d_out;
    float* out_es = out_x + xtotal;
    float* out_ed = out_es + slots;

    // ws layout: adj[B*64 uint2] | counts[B int]
    uint2* adj_g  = (uint2*)d_ws;
    int*   counts = (int*)(adj_g + (size_t)B * NAGENT);

    concat_build_kernel<<<M / ROWS_A, 256, 0, stream>>>(
        (const float4*)obs, ego, oth, (float4*)d_out, adj_g, counts);
    emit_kernel<<<B / WPB, 256, 0, stream>>>(
        adj_g, counts, out_es, out_ed, B, slots);
}

// Round 10
// 120.109 us; speedup vs baseline: 11.3074x; 1.0035x over previous
//
#include <hip/hip_runtime.h>
#include <cstdint>
#include <cstddef>

#define NAGENT 64
#define WPB 4          // batches (waves) per block
#define ROWS_A 256     // rows per block in fused concat+build (= 4 batches)
#define CAP 640        // LDS staging capacity per batch (>= 630)
#define SLOT_PB 630    // 10*(NAGENT-1) output slots per batch

// ---------------------------------------------------------------------------
// Kernel A: fused concat + edge-build. 256 rows (= 4 batches) per block.
//  - stage 256 obs rows in LDS (coalesced float4), capturing (x,y) per row
//  - write x = concat([obs, init]) as dense coalesced float4
//  - per wave: build one batch's 64x64 adjacency bitmask (dedupe +
//    (src,dst)-lex order for free), write 8B/row + per-batch count
//  - NEW vs R7: also write bsum[blockIdx] = sum of this block's 4 counts,
//    so kernel B scans 2048 ints instead of 8192 per block.
// ---------------------------------------------------------------------------
__global__ __launch_bounds__(256) void concat_build_kernel(
    const float4* __restrict__ obs4, const float* __restrict__ ego,
    const float* __restrict__ oth, float4* __restrict__ out4,
    uint2* __restrict__ adj_g, int* __restrict__ counts,
    int* __restrict__ bsum)
{
    __shared__ float  buf[ROWS_A * 16];       // 16 KB staged rows
    __shared__ float2 xy_s[ROWS_A];           // 2 KB compact (x,y)
    __shared__ int    order_s[WPB][NAGENT];   // 1 KB rank -> agent
    __shared__ unsigned int adj_s[WPB][NAGENT][2];  // 2 KB bitmatrix
    __shared__ int    cnt_s[WPB];

    const int t = threadIdx.x;
    const int wave = t >> 6;
    const int lane = t & 63;

    adj_s[wave][lane][0] = 0u;
    adj_s[wave][lane][1] = 0u;

    // Stage: 1024 float4 loads; float4 #0 of each row carries (x,y).
    const float4* src = obs4 + (size_t)blockIdx.x * (ROWS_A * 4);
    #pragma unroll
    for (int k = 0; k < 4; ++k) {
        const int f = t + k * 256;
        float4 v = src[f];
        ((float4*)buf)[f] = v;
        if ((f & 3) == 0) xy_s[f >> 2] = make_float2(v.x, v.y);
    }
    const float e0 = ego[0], e1 = ego[1];
    const float o0 = oth[0], o1 = oth[1];
    __syncthreads();

    // Concat write: 1152 float4 per block, fully coalesced.
    float4* dst = out4 + (size_t)blockIdx.x * (ROWS_A * 18 / 4);
    #pragma unroll
    for (int k = 0; k < 5; ++k) {
        const int f = t + k * 256;
        if (f >= ROWS_A * 18 / 4) break;
        float4 v;
        float* vp = (float*)&v;
        #pragma unroll
        for (int c = 0; c < 4; ++c) {
            const unsigned g   = (unsigned)(f * 4 + c);
            const unsigned row = g / 18u;
            const unsigned col = g - row * 18u;
            float val;
            if (col < 16u) {
                val = buf[row * 16u + col];
            } else {
                const bool eg = ((row & 63u) == 0u);
                val = (col == 16u) ? (eg ? e0 : o0) : (eg ? e1 : o1);
            }
            vp[c] = val;
        }
        dst[f] = v;
    }

    // Build: one wave per batch.
    const int b = blockIdx.x * WPB + wave;
    const float2 p = xy_s[wave * 64 + lane];
    const float x = p.x;

    // Stable rank by x (tie-break: original index) — all-pairs via shfl.
    int rank = 0;
    #pragma unroll 8
    for (int j = 0; j < 64; ++j) {
        float xj = __shfl(x, j);
        rank += (xj < x || (xj == x && j < lane)) ? 1 : 0;
    }
    order_s[wave][rank] = lane;
    __syncthreads();

    // Lane = sorted position. 5 lane-band masks for that agent.
    const int a = order_s[wave][lane];
    const float ya = xy_s[wave * 64 + a].y;
    const float T1 = 1.0f / 3.0f;   // == f32(1/3) in the reference
    const float T2 = 2.0f / 3.0f;
    const bool m0 = (ya <= T1) && (ya > 0.0f);
    const bool m1 = (ya > T1) && (ya <= T2);
    const bool m2 = (ya >= T2) && (ya < 1.0f);
    bool ms[5];
    ms[0] = m0; ms[1] = m1; ms[2] = m2; ms[3] = m0 || m1; ms[4] = m1 || m2;

    #pragma unroll
    for (int k = 0; k < 5; ++k) {
        unsigned long long bits = __ballot(ms[k]);
        unsigned long long higher = (lane == 63) ? 0ULL : (bits >> (lane + 1));
        if (ms[k] && higher != 0ULL) {
            int q = lane + 1 + __builtin_ctzll(higher);
            int bb = order_s[wave][q];
            atomicOr(&adj_s[wave][a][bb >> 5], 1u << (bb & 31));
            atomicOr(&adj_s[wave][bb][a >> 5], 1u << (a & 31));
        }
    }
    __syncthreads();

    const unsigned int r0 = adj_s[wave][lane][0];
    const unsigned int r1 = adj_s[wave][lane][1];
    adj_g[(size_t)b * NAGENT + lane] = make_uint2(r0, r1);

    int c = __popc(r0) + __popc(r1);
    #pragma unroll
    for (int off = 32; off >= 1; off >>= 1) c += __shfl_xor(c, off);
    if (lane == 0) { counts[b] = c; cnt_s[wave] = c; }
    __syncthreads();
    if (t == 0) bsum[blockIdx.x] = cnt_s[0] + cnt_s[1] + cnt_s[2] + cnt_s[3];
}

// ---------------------------------------------------------------------------
// Kernel B: emit + pad, no scan dispatch. Block-cooperative prefix/total
// over bsum (2048 ints, 8 KB/block vs R7's 32 KB), then each wave derives
// its batch's pre/suf with 3 L1-hot counts loads. Pad slices anchored from
// the END: X_b = 630*(B-1-b) - suffix_gt(b); batch b fills
// [slots - X_b - D_b, slots - X_b) — these tile [E, slots) exactly, so no
// block needs global E. Edges staged in LDS, aligned-f4 out.
// ---------------------------------------------------------------------------
__global__ __launch_bounds__(256) void emit_kernel(
    const uint2* __restrict__ adj_g, const int* __restrict__ counts,
    const int* __restrict__ bsum, float* __restrict__ out_es,
    float* __restrict__ out_ed, int B, int slots)
{
    __shared__ float es_s[WPB][CAP];
    __shared__ float ed_s[WPB][CAP];
    __shared__ int   red_s[2 * WPB];
    const int t = threadIdx.x;
    const int wave = t >> 6;
    const int lane = t & 63;
    const int bi = (int)blockIdx.x;
    const int b0 = bi * WPB;
    const int b = b0 + wave;
    const int NB = B / WPB;

    // Block-cooperative prefix/total over bsum (2 int4 per thread).
    int p = 0, tot = 0;
    const int4* s4 = (const int4*)bsum;
    for (int i = t; i < NB / 4; i += 256) {
        const int4 v = s4[i];
        tot += v.x + v.y + v.z + v.w;
        p += ((4 * i + 0 < bi) ? v.x : 0) + ((4 * i + 1 < bi) ? v.y : 0)
           + ((4 * i + 2 < bi) ? v.z : 0) + ((4 * i + 3 < bi) ? v.w : 0);
    }
    #pragma unroll
    for (int off = 32; off >= 1; off >>= 1) {
        p   += __shfl_xor(p, off);
        tot += __shfl_xor(tot, off);
    }
    if (lane == 0) { red_s[wave] = p; red_s[WPB + wave] = tot; }
    __syncthreads();
    p   = red_s[0] + red_s[1] + red_s[2] + red_s[3];
    tot = red_s[WPB] + red_s[WPB + 1] + red_s[WPB + 2] + red_s[WPB + 3];

    const int cnt = counts[b];        // L1-hot
    int pre = p;
    #pragma unroll
    for (int w = 0; w < WPB; ++w)
        if (w < wave) pre += counts[b0 + w];
    const int suf = tot - pre - cnt;  // sum of counts after b

    // Enumerate this row's adjacency bits into LDS staging.
    const uint2 ar = adj_g[(size_t)b * NAGENT + lane];
    unsigned int r0 = ar.x, r1 = ar.y;
    const int c = __popc(r0) + __popc(r1);
    int inc = c;
    #pragma unroll
    for (int off = 1; off < 64; off <<= 1) {
        int v = __shfl_up(inc, off);
        if (lane >= off) inc += v;
    }
    int pos = inc - c;
    const int gbase = b * NAGENT;
    const float sg = (float)(gbase + lane);
    while (r0) {
        int d = __builtin_ctz(r0); r0 &= r0 - 1u;
        es_s[wave][pos] = sg; ed_s[wave][pos] = (float)(gbase + d); ++pos;
    }
    while (r1) {
        int d = 32 + __builtin_ctz(r1); r1 &= r1 - 1u;
        es_s[wave][pos] = sg; ed_s[wave][pos] = (float)(gbase + d); ++pos;
    }
    __syncthreads();

    // ---- Edge write at [pre, pre+cnt): scalar head to 16B align, f4 body ----
    {
        int h = (4 - (pre & 3)) & 3;
        if (h > cnt) h = cnt;
        for (int j = lane; j < h; j += 64) {
            out_es[pre + j] = es_s[wave][j];
            out_ed[pre + j] = ed_s[wave][j];
        }
        const int body = (cnt - h) >> 2;      // # of float4 groups
        float4* oes4 = (float4*)(out_es + pre + h);
        float4* oed4 = (float4*)(out_ed + pre + h);
        for (int q = lane; q < body; q += 64) {
            const int j = h + 4 * q;
            float4 v, w;
            v.x = es_s[wave][j];     w.x = ed_s[wave][j];
            v.y = es_s[wave][j + 1]; w.y = ed_s[wave][j + 1];
            v.z = es_s[wave][j + 2]; w.z = ed_s[wave][j + 2];
            v.w = es_s[wave][j + 3]; w.w = ed_s[wave][j + 3];
            oes4[q] = v;
            oed4[q] = w;
        }
        for (int j = h + 4 * body + lane; j < cnt; j += 64) {
            out_es[pre + j] = es_s[wave][j];
            out_ed[pre + j] = ed_s[wave][j];
        }
    }

    // ---- Pad slice write (batch-owned, end-anchored), vectorized -1 fill ----
    {
        const int D = SLOT_PB - cnt;
        const int X = SLOT_PB * (B - 1 - b) - suf;
        const int pbeg = slots - X - D;
        int h = (4 - (pbeg & 3)) & 3;
        if (h > D) h = D;
        for (int j = lane; j < h; j += 64) {
            out_es[pbeg + j] = -1.0f;
            out_ed[pbeg + j] = -1.0f;
        }
        const int body = (D - h) >> 2;
        float4* oes4 = (float4*)(out_es + pbeg + h);
        float4* oed4 = (float4*)(out_ed + pbeg + h);
        const float4 neg1 = make_float4(-1.0f, -1.0f, -1.0f, -1.0f);
        for (int q = lane; q < body; q += 64) {
            oes4[q] = neg1;
            oed4[q] = neg1;
        }
        for (int j = h + 4 * body + lane; j < D; j += 64) {
            out_es[pbeg + j] = -1.0f;
            out_ed[pbeg + j] = -1.0f;
        }
    }
}

// ---------------------------------------------------------------------------
extern "C" void kernel_launch(void* const* d_in, const int* in_sizes, int n_in,
                              void* d_out, int out_size, void* d_ws, size_t ws_size,
                              hipStream_t stream)
{
    const float* obs = (const float*)d_in[0];
    const float* ego = (const float*)d_in[1];
    const float* oth = (const float*)d_in[2];

    const int B = in_sizes[0] / (NAGENT * 16);        // 8192
    const int M = B * NAGENT;                          // 524288 rows
    const int xtotal = M * 18;                         // 9437184
    const int slots = B * SLOT_PB;                     // 5160960

    float* out_x  = (float*)d_out;
    float* out_es = out_x + xtotal;
    float* out_ed = out_es + slots;

    // ws layout: adj[B*64 uint2] | counts[B int] | bsum[B/WPB int]
    uint2* adj_g  = (uint2*)d_ws;
    int*   counts = (int*)(adj_g + (size_t)B * NAGENT);
    int*   bsum   = counts + B;

    concat_build_kernel<<<M / ROWS_A, 256, 0, stream>>>(
        (const float4*)obs, ego, oth, (float4*)d_out, adj_g, counts, bsum);
    emit_kernel<<<B / WPB, 256, 0, stream>>>(
        adj_g, counts, bsum, out_es, out_ed, B, slots);
}